// Round 3
// baseline (406.297 us; speedup 1.0000x reference)
//
#include <hip/hip_runtime.h>
#include <math.h>

#define TB 128
#define TT 4096
#define TD 64

// ---- workspace layout (bytes): zeroed prefix first, xmean (no zero) last ----
#define GRAM_OFF   0u
#define HIST_OFF   2097152u
#define COLSUM_OFF 4194304u
#define SCAL_OFF   4227072u
#define FIRST_OFF  4230656u
#define ZERO_BYTES 4231168u
#define XMEAN_OFF  4231168u

typedef float  f32x4  __attribute__((ext_vector_type(4)));
typedef short  s16x8  __attribute__((ext_vector_type(8)));

__device__ __forceinline__ float brs4(float v, float* sbuf, int tid) {
#pragma unroll
  for (int o = 32; o; o >>= 1) v += __shfl_xor(v, o);
  __syncthreads();
  if ((tid & 63) == 0) sbuf[tid >> 6] = v;
  __syncthreads();
  return (sbuf[0] + sbuf[1]) + (sbuf[2] + sbuf[3]);
}

__device__ __forceinline__ float brs8(float v, float* sbuf, int tid) {
#pragma unroll
  for (int o = 32; o; o >>= 1) v += __shfl_xor(v, o);
  __syncthreads();
  if ((tid & 63) == 0) sbuf[tid >> 6] = v;
  __syncthreads();
  return ((sbuf[0] + sbuf[1]) + (sbuf[2] + sbuf[3])) +
         ((sbuf[4] + sbuf[5]) + (sbuf[6] + sbuf[7]));
}

__device__ __forceinline__ int binof(float v) {
  int bi = (int)floorf(fmaf(v, 256.f, 2048.f));
  return bi < 0 ? 0 : (bi > 4095 ? 4095 : bi);
}

__device__ __forceinline__ unsigned short f2bf(float f) {  // RNE f32->bf16
  unsigned u = __float_as_uint(f);
  return (unsigned short)((u + 0x7FFFu + ((u >> 16) & 1u)) >> 16);
}

// ============ kernel 1: fused x+mask pass (stats, hist, xmean, MFMA gram) ============
// grid (8, 128): 512 timesteps (8 tiles of 64) per block. LDS ~37 KB -> 4 blocks/CU.
__global__ __launch_bounds__(256) void k1_fused(const float* __restrict__ x,
    const float* __restrict__ mk, float* __restrict__ xmean,
    float* __restrict__ gram, unsigned* __restrict__ hist,
    float* __restrict__ colsum, float* __restrict__ scal,
    int* __restrict__ firstg) {
  __shared__ __align__(16) unsigned short Xt[2][64 * 72]; // bf16, d-major, dbuf
  __shared__ unsigned shist[4096];
  __shared__ float bnd[2][4][64];                         // boundary rows 0/16/32/48
  __shared__ float scol[64];
  __shared__ float sred[4];
  __shared__ int smax[4];

  const int tid  = threadIdx.x;
  const int b    = blockIdx.y;
  const int s    = blockIdx.x;
  const int t0   = s << 9;             // 512 timesteps per block
  const int lane = tid & 63;
  const int wv   = tid >> 6;
  const int g    = tid >> 4;           // row-group 0..15 (4 rows each)
  const int r0   = g << 2;
  const int c    = tid & 15;
  const int lcol = c << 2;
  // MFMA: wave wv owns 32x32 quadrant, 2x2 16x16 blocks
  const int mb0 = (wv & 1) << 5;
  const int nb0 = (wv >> 1) << 5;
  const int ml  = lane & 15;
  const int qk  = (lane >> 4) << 3;

  for (int i = tid; i < 4096; i += 256) shist[i] = 0u;
  if (tid < 64) scol[tid] = 0.f;

  float s1 = 0.f, s2 = 0.f, s3 = 0.f, s4 = 0.f, ac = 0.f;
  float osum = 0.f, o2 = 0.f;
  int fmax = 0;
  float cs[4] = {0.f, 0.f, 0.f, 0.f};
  f32x4 acc[2][2];
#pragma unroll
  for (int mi = 0; mi < 2; ++mi)
#pragma unroll
    for (int ni = 0; ni < 2; ++ni) acc[mi][ni] = (f32x4)0.f;

  const float* xb = x + (size_t)b * (TT * TD);
  const float* mbp = mk + (size_t)b * (TT * TD);

  // ---- prologue: load tile 0 ----
  float4 v[4], mv[4];
#pragma unroll
  for (int k = 0; k < 4; ++k) {
    v[k]  = *(const float4*)(xb  + (size_t)(t0 + r0 + k) * TD + lcol);
    mv[k] = *(const float4*)(mbp + (size_t)(t0 + r0 + k) * TD + lcol);
  }

  int p = 0;
  for (int tile = 0; tile < 8; ++tile) {
    const int tbase = t0 + (tile << 6);
    // ---- stage: bf16 transpose into Xt[p] (rotated j -> 4-way instead of 8-way) ----
#pragma unroll
    for (int j = 0; j < 4; ++j) {
      const int jj = (j + c + g) & 3;
      uint2 pw;
      pw.x = (unsigned)f2bf((&v[0].x)[jj]) | ((unsigned)f2bf((&v[1].x)[jj]) << 16);
      pw.y = (unsigned)f2bf((&v[2].x)[jj]) | ((unsigned)f2bf((&v[3].x)[jj]) << 16);
      *(uint2*)(&Xt[p][(lcol + jj) * 72 + r0]) = pw;
    }
    if ((g & 3) == 0) *(float4*)(&bnd[p][g >> 2][lcol]) = v[0];
    __syncthreads();
    // ---- prefetch next tile into registers (overlaps MFMA/stats below) ----
    float4 vn[4], mn[4];
    if (tile < 7) {
      const int tn = tbase + 64;
#pragma unroll
      for (int k = 0; k < 4; ++k) {
        vn[k] = *(const float4*)(xb  + (size_t)(tn + r0 + k) * TD + lcol);
        mn[k] = *(const float4*)(mbp + (size_t)(tn + r0 + k) * TD + lcol);
      }
    }
    // ---- MFMA gram on Xt[p]: K=64 in two 32-chunks ----
#pragma unroll
    for (int kk = 0; kk < 2; ++kk) {
      const int ko = (kk << 5) + qk;
      s16x8 af[2], bf[2];
#pragma unroll
      for (int mi = 0; mi < 2; ++mi)
        af[mi] = *(const s16x8*)(&Xt[p][(mb0 + (mi << 4) + ml) * 72 + ko]);
#pragma unroll
      for (int ni = 0; ni < 2; ++ni)
        bf[ni] = *(const s16x8*)(&Xt[p][(nb0 + (ni << 4) + ml) * 72 + ko]);
#pragma unroll
      for (int mi = 0; mi < 2; ++mi)
#pragma unroll
        for (int ni = 0; ni < 2; ++ni)
          acc[mi][ni] = __builtin_amdgcn_mfma_f32_16x16x32_bf16(
              af[mi], bf[ni], acc[mi][ni], 0, 0, 0);
    }
    // ---- elementwise stats + histogram (current tile, from registers) ----
#pragma unroll
    for (int k = 0; k < 4; ++k) {
      const float x0 = v[k].x, x1 = v[k].y, x2 = v[k].z, x3 = v[k].w;
      const float q0 = x0 * x0, q1 = x1 * x1, q2 = x2 * x2, q3 = x3 * x3;
      s1 += (x0 + x1) + (x2 + x3);
      s2 += (q0 + q1) + (q2 + q3);
      s3 += (q0 * x0 + q1 * x1) + (q2 * x2 + q3 * x3);
      s4 += (q0 * q0 + q1 * q1) + (q2 * q2 + q3 * q3);
      cs[0] += x0; cs[1] += x1; cs[2] += x2; cs[3] += x3;
      atomicAdd(&shist[binof(x0)], 1u);
      atomicAdd(&shist[binof(x1)], 1u);
      atomicAdd(&shist[binof(x2)], 1u);
      atomicAdd(&shist[binof(x3)], 1u);
    }
    // ---- row sums (x + mask) via 16-lane shfl reduction ----
#pragma unroll
    for (int k = 0; k < 4; ++k) {
      float rx = (v[k].x + v[k].y) + (v[k].z + v[k].w);
      float rm = (mv[k].x + mv[k].y) + (mv[k].z + mv[k].w);
      rx += __shfl_xor(rx, 1); rm += __shfl_xor(rm, 1);
      rx += __shfl_xor(rx, 2); rm += __shfl_xor(rm, 2);
      rx += __shfl_xor(rx, 4); rm += __shfl_xor(rm, 4);
      rx += __shfl_xor(rx, 8); rm += __shfl_xor(rm, 8);
      if (c == 0) {
        const int t = tbase + r0 + k;
        xmean[(size_t)b * TT + t] = rx * (1.f / 64.f);
        osum += rm;
        o2 = fmaf(rm, rm, o2);
        if (rm > 0.f) fmax = max(fmax, TT - t);
      }
    }
    // ---- lag-1 autocorr: 3 local row-pair dots + boundary ----
    {
      float dot =
          (v[0].x * v[1].x + v[0].y * v[1].y) + (v[0].z * v[1].z + v[0].w * v[1].w) +
          (v[1].x * v[2].x + v[1].y * v[2].y) + (v[1].z * v[2].z + v[1].w * v[2].w) +
          (v[2].x * v[3].x + v[2].y * v[3].y) + (v[2].z * v[3].z + v[2].w * v[3].w);
      if ((g & 3) == 3) {
        float4 nx;
        bool have = true;
        if (g < 15) {
          nx = *(const float4*)(&bnd[p][(g >> 2) + 1][lcol]);
        } else if (tbase + 64 < TT) {
          nx = *(const float4*)(xb + (size_t)(tbase + 64) * TD + lcol);
        } else {
          have = false;
        }
        if (have)
          dot += (v[3].x * nx.x + v[3].y * nx.y) + (v[3].z * nx.z + v[3].w * nx.w);
      }
      ac += dot;
    }
    // ---- advance pipeline ----
    if (tile < 7) {
#pragma unroll
      for (int k = 0; k < 4; ++k) { v[k] = vn[k]; mv[k] = mn[k]; }
    }
    p ^= 1;
  }

  // ---- scalar reductions ----
  const float rac = brs4(ac, sred, tid);
  const float r1 = brs4(s1, sred, tid);
  const float r2 = brs4(s2, sred, tid);
  const float r3 = brs4(s3, sred, tid);
  const float r4 = brs4(s4, sred, tid);
  const float ro = brs4(osum, sred, tid);
  const float ro2 = brs4(o2, sred, tid);
#pragma unroll
  for (int o = 32; o; o >>= 1) fmax = max(fmax, __shfl_xor(fmax, o));
  if ((tid & 63) == 0) smax[tid >> 6] = fmax;
  __syncthreads();
  if (tid == 0) {
    atomicAdd(&scal[0 * TB + b], rac);
    atomicAdd(&scal[1 * TB + b], r1);
    atomicAdd(&scal[2 * TB + b], r2);
    atomicAdd(&scal[3 * TB + b], r3);
    atomicAdd(&scal[4 * TB + b], r4);
    atomicAdd(&scal[5 * TB + b], ro);
    atomicAdd(&scal[6 * TB + b], ro2);
    atomicMax(&firstg[b], max(max(smax[0], smax[1]), max(smax[2], smax[3])));
  }
  // ---- column sums ----
#pragma unroll
  for (int cc = 0; cc < 4; ++cc) atomicAdd(&scol[lcol + cc], cs[cc]);
  __syncthreads();
  if (tid < 64) atomicAdd(&colsum[b * 64 + tid], scol[tid]);
  // ---- gram accumulate: C/D layout col=lane&15, row=(lane>>4)*4+reg ----
  float* gb = gram + (size_t)b * 4096;
  {
    const int crow = (lane >> 4) << 2;
    const int ccol = lane & 15;
#pragma unroll
    for (int mi = 0; mi < 2; ++mi)
#pragma unroll
      for (int ni = 0; ni < 2; ++ni) {
        const int gr0 = mb0 + (mi << 4) + crow;
        const int gc = nb0 + (ni << 4) + ccol;
#pragma unroll
        for (int rg = 0; rg < 4; ++rg)
          atomicAdd(&gb[(gr0 + rg) * 64 + gc], acc[mi][ni][rg]);
      }
  }
  // ---- histogram flush ----
  unsigned* hb = hist + (size_t)b * 4096;
  for (int i = tid; i < 4096; i += 256) {
    const unsigned hv = shist[i];
    if (hv) atomicAdd(&hb[i], hv);
  }
}

// ============ kernel 34: block-specialized spectral (0..127) + final (128..255) ============
__global__ __launch_bounds__(512) void k34(const float* __restrict__ xmean,
    const float* __restrict__ gram, const float* __restrict__ colsum,
    const unsigned* __restrict__ hist, const float* __restrict__ scal,
    const int* __restrict__ firstg, float* __restrict__ out) {
  __shared__ __align__(16) char arena[49152];
  __shared__ float sred[8];
  __shared__ float smv[8];
  __shared__ int smi[8];
  __shared__ float cssh[64];
  __shared__ float sdsh[64];
  __shared__ float osv_s[6];
  const int tid = threadIdx.x;

  if (blockIdx.x < 128) {
    // ================= spectral path =================
    const int b = blockIdx.x;
    float* xm = (float*)arena;
    float* re = xm + 4096;
    float* im = re + 4096;
    const float* xb = xmean + (size_t)b * TT;
    for (int i = tid; i < TT; i += 512) xm[i] = xb[i];
    __syncthreads();
    float ls = 0.f;
    for (int i = tid; i < TT; i += 512) ls += xm[i];
    const float meanv = brs8(ls, sred, tid) * (1.f / TT);
    float tnum = 0.f, roc = 0.f;
    int pk = 0, zc = 0;
    for (int i = tid; i < TT; i += 512) {
      const float xi = xm[i];
      tnum += ((float)i - 2047.5f) * (xi - meanv);
      if (i < TT - 1) {
        const float d1 = xm[i + 1] - xi;
        roc += fabsf(d1);
        if (i >= 1) {
          const float d0 = xi - xm[i - 1];
          if (d1 * d0 < 0.f) ++pk;
        }
      }
      if (i >= 1) {
        if ((xi - meanv) * (xm[i - 1] - meanv) < 0.f) ++zc;
      }
    }
    tnum = brs8(tnum, sred, tid);
    roc = brs8(roc, sred, tid);
    const float pkf = brs8((float)pk, sred, tid);
    const float zcf = brs8((float)zc, sred, tid);
    if (tid == 0) {
      out[b * 17 + 1] = tnum / 5726622720.0f;
      out[b * 17 + 9] = pkf * (1.f / 4094.f);
      out[b * 17 + 10] = zcf * (1.f / 4095.f);
      out[b * 17 + 11] = roc * (1.f / 4095.f);
    }
    // radix-2 DIT FFT in LDS
    for (int i = tid; i < TT; i += 512) {
      re[i] = xm[__brev((unsigned)i) >> 20];
      im[i] = 0.f;
    }
    __syncthreads();
    int l2h = 0;
    for (int len = 2; len <= TT; len <<= 1, ++l2h) {
      const int half = len >> 1;
      const float ab = -6.283185307179586f / (float)len;
      for (int j = tid; j < TT / 2; j += 512) {
        const int pos = j & (half - 1);
        const int i0 = ((j >> l2h) << (l2h + 1)) + pos;
        const int i1 = i0 + half;
        float sn, cn;
        __sincosf(ab * (float)pos, &sn, &cn);
        const float vr = re[i1], vi = im[i1];
        const float tr = cn * vr - sn * vi;
        const float ti = cn * vi + sn * vr;
        const float ur = re[i0], ui = im[i0];
        re[i0] = ur + tr; im[i0] = ui + ti;
        re[i1] = ur - tr; im[i1] = ui - ti;
      }
      __syncthreads();
    }
    // power spectrum: sum, argmax, entropy over bins 0..2048
    float ps = 0.f, bmaxv = -1.f;
    int bidx = 0;
    for (int k = tid; k <= 2048; k += 512) {
      const float p = re[k] * re[k] + im[k] * im[k];
      ps += p;
      if (p > bmaxv) { bmaxv = p; bidx = k; }
    }
    ps = brs8(ps, sred, tid);
#pragma unroll
    for (int o = 32; o; o >>= 1) {
      const float ov = __shfl_xor(bmaxv, o);
      const int oi = __shfl_xor(bidx, o);
      if (ov > bmaxv || (ov == bmaxv && oi < bidx)) { bmaxv = ov; bidx = oi; }
    }
    if ((tid & 63) == 0) { smv[tid >> 6] = bmaxv; smi[tid >> 6] = bidx; }
    __syncthreads();
    float ent = 0.f;
    const float inv = 1.f / (ps + 1e-8f);
    for (int k = tid; k <= 2048; k += 512) {
      const float p = (re[k] * re[k] + im[k] * im[k]) * inv;
      ent -= p * __logf(p + 1e-8f);
    }
    ent = brs8(ent, sred, tid);
    if (tid == 0) {
      float bv = smv[0]; int bi = smi[0];
      for (int w = 1; w < 8; ++w)
        if (smv[w] > bv || (smv[w] == bv && smi[w] < bi)) { bv = smv[w]; bi = smi[w]; }
      out[b * 17 + 2] = (float)bi * (1.f / 2048.f);
      out[b * 17 + 3] = ent;
    }
  } else {
    // ================= final path =================
    const int b = blockIdx.x - 128;
    float* Lg = (float*)arena;                          // 64 x 65
    unsigned* h = (unsigned*)(arena + 16640);           // 4096
    unsigned* cumc = (unsigned*)(arena + 16640 + 16384);// 256
    if (tid < 64) cssh[tid] = colsum[b * 64 + tid];
    for (int i = tid; i < 4096; i += 512) h[i] = hist[(size_t)b * 4096 + i];
    __syncthreads();
    const float* gb = gram + (size_t)b * 4096;
    for (int i = tid; i < 4096; i += 512) {
      const int d = i >> 6, e = i & 63;
      Lg[d * 65 + e] = gb[i] - cssh[d] * cssh[e] * (1.f / 4096.f);
    }
    unsigned chs_own = 0;
    if (tid < 256) {
#pragma unroll
      for (int j = 0; j < 16; ++j) chs_own += h[(tid << 4) + j];
      cumc[tid] = chs_own;
    }
    __syncthreads();
    if (tid < 64) sdsh[tid] = sqrtf(Lg[tid * 65 + tid] * (1.f / 4095.f));
    // inclusive scan over 256 coarse bins
    for (int off = 1; off < 256; off <<= 1) {
      unsigned add = 0;
      if (tid < 256 && tid >= off) add = cumc[tid - off];
      __syncthreads();
      if (tid < 256) cumc[tid] += add;
      __syncthreads();
    }
    float mcs = 0.f, trc = 0.f;
    for (int i = tid; i < 4096; i += 512) {
      const int d = i >> 6, e = i & 63;
      const float gv = Lg[d * 65 + e];
      if (d != e) mcs += (gv * (1.f / 4095.f)) / (sdsh[d] * sdsh[e] + 1e-8f);
      else trc += gv;
    }
    mcs = brs8(mcs, sred, tid);
    trc = brs8(trc, sred, tid);
    // parallel quantile refinement
    if (tid < 256) {
      const unsigned ranks[6] = {65535u, 65536u, 131071u, 131072u, 196607u, 196608u};
      const unsigned incl = cumc[tid];
      const unsigned excl = incl - chs_own;
#pragma unroll
      for (int qi = 0; qi < 6; ++qi) {
        const unsigned r = ranks[qi];
        if (excl <= r && r < incl) {
          int bin = tid << 4;
          unsigned cum = excl;
          while (bin < 4095 && cum + h[bin] <= r) { cum += h[bin]; ++bin; }
          const float cnt = (float)max(h[bin], 1u);
          osv_s[qi] = ((float)bin * (1.f / 256.f) - 8.f) +
                      (((float)(r - cum) + 0.5f) / cnt) * (1.f / 256.f);
        }
      }
    }
    // power iteration on wave 0
    float lam = 0.f;
    if (tid < 64) {
      const float* rowp = &Lg[tid * 65];
      float v = 1.f + 0.001f * (float)tid;
      float n2 = 1.f;
      for (int it = 0; it < 48; ++it) {
        float w0 = 0.f, w1 = 0.f, w2 = 0.f, w3 = 0.f;
#pragma unroll
        for (int e = 0; e < 64; e += 4) {
          w0 = fmaf(rowp[e],     __shfl(v, e),     w0);
          w1 = fmaf(rowp[e + 1], __shfl(v, e + 1), w1);
          w2 = fmaf(rowp[e + 2], __shfl(v, e + 2), w2);
          w3 = fmaf(rowp[e + 3], __shfl(v, e + 3), w3);
        }
        const float w = (w0 + w1) + (w2 + w3);
        n2 = w * w;
#pragma unroll
        for (int o = 32; o; o >>= 1) n2 += __shfl_xor(n2, o);
        v = w * rsqrtf(n2);
      }
      lam = sqrtf(n2);
    }
    __syncthreads();
    if (tid == 0) {
      const float q25 = 0.25f * osv_s[0] + 0.75f * osv_s[1];
      const float q50 = 0.5f * (osv_s[2] + osv_s[3]);
      const float q75 = 0.75f * osv_s[4] + 0.25f * osv_s[5];
      const float N = 262144.f;
      const float m1 = scal[1 * TB + b] / N;
      const float M2 = scal[2 * TB + b] / N;
      const float M3 = scal[3 * TB + b] / N;
      const float M4 = scal[4 * TB + b] / N;
      const float mu2 = M2 - m1 * m1;
      const float mu3 = M3 - 3.f * m1 * M2 + 2.f * m1 * m1 * m1;
      const float mu4 = M4 - 4.f * m1 * M3 + 6.f * m1 * m1 * M2 - 3.f * m1 * m1 * m1 * m1;
      const float skew = mu3 / (sqrtf(mu2) * mu2 + 1e-8f);
      const float kurt = mu4 / (mu2 * mu2 + 1e-8f);
      const float acv = scal[0 * TB + b] * (1.f / 262080.f);
      const float msum = scal[5 * TB + b];
      const float o2s = scal[6 * TB + b];
      const float missing = 1.f - msum / 262144.f;
      const float sdm = msum * (1.f / 64.f) * (1.f / 4096.f);
      const float dvar = (o2s * (1.f / 4096.f) - 4096.f * sdm * sdm) * (1.f / 4095.f);
      const int fm = firstg[b];
      const float fobs = fm > 0 ? (float)(4096 - fm) * (1.f / 4096.f) : 0.f;
      float* ob = out + b * 17;
      ob[0] = acv;
      ob[4] = skew; ob[5] = kurt;
      ob[6] = q25; ob[7] = q50; ob[8] = q75;
      ob[12] = missing; ob[13] = dvar; ob[14] = fobs;
      ob[15] = mcs / (4032.f + 1e-8f);
      ob[16] = lam / trc;
    }
  }
}

extern "C" void kernel_launch(void* const* d_in, const int* in_sizes, int n_in,
                              void* d_out, int out_size, void* d_ws, size_t ws_size,
                              hipStream_t stream) {
  (void)in_sizes; (void)n_in; (void)out_size; (void)ws_size;
  const float* x = (const float*)d_in[0];
  const float* mask = (const float*)d_in[1];
  float* out = (float*)d_out;
  char* ws = (char*)d_ws;
  float* gram = (float*)(ws + GRAM_OFF);
  unsigned* hist = (unsigned*)(ws + HIST_OFF);
  float* colsum = (float*)(ws + COLSUM_OFF);
  float* scal = (float*)(ws + SCAL_OFF);
  int* firstg = (int*)(ws + FIRST_OFF);
  float* xmean = (float*)(ws + XMEAN_OFF);

  hipMemsetAsync(d_ws, 0, ZERO_BYTES, stream);

  dim3 g1(8, TB);
  k1_fused<<<g1, 256, 0, stream>>>(x, mask, xmean, gram, hist, colsum, scal, firstg);
  k34<<<256, 512, 0, stream>>>(xmean, gram, colsum, hist, scal, firstg, out);
}

// Round 4
// 349.133 us; speedup vs baseline: 1.1637x; 1.1637x over previous
//
#include <hip/hip_runtime.h>
#include <math.h>

#define TB 128
#define TT 4096
#define TD 64

// ---- workspace layout (bytes): zeroed prefix first, xmean (no zero) last ----
#define GRAM_OFF   0u
#define HIST_OFF   2097152u
#define COLSUM_OFF 4194304u
#define SCAL_OFF   4227072u
#define FIRST_OFF  4230656u
#define ZERO_BYTES 4231168u
#define XMEAN_OFF  4231168u

typedef float  f32x4  __attribute__((ext_vector_type(4)));
typedef short  s16x8  __attribute__((ext_vector_type(8)));

__device__ __forceinline__ float brs4(float v, float* sbuf, int tid) {
#pragma unroll
  for (int o = 32; o; o >>= 1) v += __shfl_xor(v, o);
  __syncthreads();
  if ((tid & 63) == 0) sbuf[tid >> 6] = v;
  __syncthreads();
  return (sbuf[0] + sbuf[1]) + (sbuf[2] + sbuf[3]);
}

__device__ __forceinline__ float brs8(float v, float* sbuf, int tid) {
#pragma unroll
  for (int o = 32; o; o >>= 1) v += __shfl_xor(v, o);
  __syncthreads();
  if ((tid & 63) == 0) sbuf[tid >> 6] = v;
  __syncthreads();
  return ((sbuf[0] + sbuf[1]) + (sbuf[2] + sbuf[3])) +
         ((sbuf[4] + sbuf[5]) + (sbuf[6] + sbuf[7]));
}

__device__ __forceinline__ int binof(float v) {
  int bi = (int)floorf(fmaf(v, 256.f, 2048.f));
  return bi < 0 ? 0 : (bi > 4095 ? 4095 : bi);
}

__device__ __forceinline__ unsigned short f2bf(float f) {  // RNE f32->bf16
  unsigned u = __float_as_uint(f);
  return (unsigned short)((u + 0x7FFFu + ((u >> 16) & 1u)) >> 16);
}

// ============ kernel A: pure streaming stats (x + mask), no in-loop barriers ============
// grid (8, 128): 512 timesteps per block; wave wv owns 128 consecutive t.
__global__ __launch_bounds__(256) void kA_stats(const float* __restrict__ x,
    const float* __restrict__ mk, float* __restrict__ xmean,
    unsigned* __restrict__ hist, float* __restrict__ colsum,
    float* __restrict__ scal, int* __restrict__ firstg) {
  __shared__ unsigned shist[4096];
  __shared__ float xrow[512];
  __shared__ float scol[64];
  __shared__ float sred[4];
  __shared__ int smax[4];

  const int tid  = threadIdx.x;
  const int b    = blockIdx.y;
  const int s    = blockIdx.x;
  const int t0   = s << 9;            // 512 timesteps per block
  const int lane = tid & 63;
  const int wv   = tid >> 6;
  const int q    = lane >> 4;         // row-in-group 0..3
  const int c    = lane & 15;         // column group (4 floats)
  const int lcol = c << 2;
  const int tw   = t0 + (wv << 7);    // wave's 128-t range

  for (int i = tid; i < 4096; i += 256) shist[i] = 0u;
  if (tid < 64) scol[tid] = 0.f;
  __syncthreads();

  float s1 = 0.f, s2 = 0.f, s3 = 0.f, s4 = 0.f, ac = 0.f;
  float osum = 0.f, o2 = 0.f;
  int fmax = 0;
  float cs0 = 0.f, cs1 = 0.f, cs2 = 0.f, cs3 = 0.f;
  float4 pv = make_float4(0.f, 0.f, 0.f, 0.f);

  const float* xb = x + (size_t)b * (TT * TD);
  const float* mb = mk + (size_t)b * (TT * TD);

  for (int it = 0; it < 32; ++it) {
    const int t = tw + (it << 2) + q;
    const float4 v = *(const float4*)(xb + (size_t)t * TD + lcol);
    const float4 m = *(const float4*)(mb + (size_t)t * TD + lcol);
    // ---- moments / colsum / histogram ----
    {
      const float x0 = v.x, x1 = v.y, x2 = v.z, x3 = v.w;
      const float q0 = x0 * x0, q1 = x1 * x1, q2 = x2 * x2, q3 = x3 * x3;
      s1 += (x0 + x1) + (x2 + x3);
      s2 += (q0 + q1) + (q2 + q3);
      s3 += (q0 * x0 + q1 * x1) + (q2 * x2 + q3 * x3);
      s4 += (q0 * q0 + q1 * q1) + (q2 * q2 + q3 * q3);
      cs0 += x0; cs1 += x1; cs2 += x2; cs3 += x3;
      atomicAdd(&shist[binof(x0)], 1u);
      atomicAdd(&shist[binof(x1)], 1u);
      atomicAdd(&shist[binof(x2)], 1u);
      atomicAdd(&shist[binof(x3)], 1u);
    }
    // ---- row sums (x + mask) across 16 lanes ----
    {
      float rx = (v.x + v.y) + (v.z + v.w);
      float rm = (m.x + m.y) + (m.z + m.w);
      rx += __shfl_xor(rx, 1); rm += __shfl_xor(rm, 1);
      rx += __shfl_xor(rx, 2); rm += __shfl_xor(rm, 2);
      rx += __shfl_xor(rx, 4); rm += __shfl_xor(rm, 4);
      rx += __shfl_xor(rx, 8); rm += __shfl_xor(rm, 8);
      if (c == 0) {
        xrow[t - t0] = rx * (1.f / 64.f);
        osum += rm;
        o2 = fmaf(rm, rm, o2);
        if (rm > 0.f) fmax = max(fmax, TT - t);
      }
    }
    // ---- lag-1 autocorr: in-wave pairs (q,q+1) ----
    {
      const float n0 = __shfl(v.x, lane + 16);
      const float n1 = __shfl(v.y, lane + 16);
      const float n2 = __shfl(v.z, lane + 16);
      const float n3 = __shfl(v.w, lane + 16);
      const float d1 = (v.x * n0 + v.y * n1) + (v.z * n2 + v.w * n3);
      ac += (q < 3) ? d1 : 0.f;
      // cross-iter pair (prev q3 row, current q0 row), computed on q3 lanes
      const float b0 = __shfl(v.x, c);
      const float b1 = __shfl(v.y, c);
      const float b2 = __shfl(v.z, c);
      const float b3 = __shfl(v.w, c);
      if (it > 0) {
        const float d2 = (pv.x * b0 + pv.y * b1) + (pv.z * b2 + pv.w * b3);
        ac += (q == 3) ? d2 : 0.f;
      }
      pv = v;
    }
  }
  // ---- final boundary pair (tw+127, tw+128) ----
  {
    const int tnext = tw + 128;
    if (tnext < TT) {
      const float4 nb = *(const float4*)(xb + (size_t)tnext * TD + lcol);
      const float d2 = (pv.x * nb.x + pv.y * nb.y) + (pv.z * nb.z + pv.w * nb.w);
      ac += (q == 3) ? d2 : 0.f;
    }
  }
  __syncthreads();
  // ---- xmean flush (coalesced) ----
  xmean[(size_t)b * TT + t0 + tid] = xrow[tid];
  xmean[(size_t)b * TT + t0 + tid + 256] = xrow[tid + 256];
  // ---- scalar reductions ----
  const float rac = brs4(ac, sred, tid);
  const float r1 = brs4(s1, sred, tid);
  const float r2 = brs4(s2, sred, tid);
  const float r3 = brs4(s3, sred, tid);
  const float r4 = brs4(s4, sred, tid);
  const float ro = brs4(osum, sred, tid);
  const float ro2 = brs4(o2, sred, tid);
#pragma unroll
  for (int o = 32; o; o >>= 1) fmax = max(fmax, __shfl_xor(fmax, o));
  if ((tid & 63) == 0) smax[tid >> 6] = fmax;
  __syncthreads();
  if (tid == 0) {
    atomicAdd(&scal[0 * TB + b], rac);
    atomicAdd(&scal[1 * TB + b], r1);
    atomicAdd(&scal[2 * TB + b], r2);
    atomicAdd(&scal[3 * TB + b], r3);
    atomicAdd(&scal[4 * TB + b], r4);
    atomicAdd(&scal[5 * TB + b], ro);
    atomicAdd(&scal[6 * TB + b], ro2);
    atomicMax(&firstg[b], max(max(smax[0], smax[1]), max(smax[2], smax[3])));
  }
  // ---- column sums ----
  atomicAdd(&scol[lcol + 0], cs0);
  atomicAdd(&scol[lcol + 1], cs1);
  atomicAdd(&scol[lcol + 2], cs2);
  atomicAdd(&scol[lcol + 3], cs3);
  __syncthreads();
  if (tid < 64) atomicAdd(&colsum[b * 64 + tid], scol[tid]);
  // ---- histogram flush ----
  unsigned* hb = hist + (size_t)b * 4096;
  for (int i = tid; i < 4096; i += 256) {
    const unsigned hv = shist[i];
    if (hv) atomicAdd(&hb[i], hv);
  }
}

// ============ kernel B: gram only (bf16 MFMA), double-buffered, 1 barrier/tile ============
// grid (8, 128): 512 timesteps per block, 8 tiles of 64.
__global__ __launch_bounds__(256) void kB_gram(const float* __restrict__ x,
                                               float* __restrict__ gram) {
  __shared__ __align__(16) unsigned short Xt[2][64 * 72]; // bf16, d-major
  const int tid  = threadIdx.x;
  const int b    = blockIdx.y;
  const int s    = blockIdx.x;
  const int t0   = s << 9;
  const int lane = tid & 63;
  const int wv   = tid >> 6;
  const int g    = tid >> 4;
  const int r0   = g << 2;
  const int c    = tid & 15;
  const int lcol = c << 2;
  const int mb0 = (wv & 1) << 5;
  const int nb0 = (wv >> 1) << 5;
  const int ml  = lane & 15;
  const int qk  = (lane >> 4) << 3;

  f32x4 acc[2][2];
#pragma unroll
  for (int mi = 0; mi < 2; ++mi)
#pragma unroll
    for (int ni = 0; ni < 2; ++ni) acc[mi][ni] = (f32x4)0.f;

  const float* xb = x + (size_t)b * (TT * TD);

  int p = 0;
  for (int tile = 0; tile < 8; ++tile) {
    const int tbase = t0 + (tile << 6);
    float4 v[4];
#pragma unroll
    for (int k = 0; k < 4; ++k)
      v[k] = *(const float4*)(xb + (size_t)(tbase + r0 + k) * TD + lcol);
    // static bf16 transpose into Xt[p] (no dynamic indexing)
#pragma unroll
    for (int j = 0; j < 4; ++j) {
      const float e0 = j == 0 ? v[0].x : (j == 1 ? v[0].y : (j == 2 ? v[0].z : v[0].w));
      const float e1 = j == 0 ? v[1].x : (j == 1 ? v[1].y : (j == 2 ? v[1].z : v[1].w));
      const float e2 = j == 0 ? v[2].x : (j == 1 ? v[2].y : (j == 2 ? v[2].z : v[2].w));
      const float e3 = j == 0 ? v[3].x : (j == 1 ? v[3].y : (j == 2 ? v[3].z : v[3].w));
      uint2 pw;
      pw.x = (unsigned)f2bf(e0) | ((unsigned)f2bf(e1) << 16);
      pw.y = (unsigned)f2bf(e2) | ((unsigned)f2bf(e3) << 16);
      *(uint2*)(&Xt[p][(lcol + j) * 72 + r0]) = pw;
    }
    __syncthreads();
    // MFMA: K=64 in two 32-chunks
#pragma unroll
    for (int kk = 0; kk < 2; ++kk) {
      const int ko = (kk << 5) + qk;
      s16x8 af[2], bf[2];
#pragma unroll
      for (int mi = 0; mi < 2; ++mi)
        af[mi] = *(const s16x8*)(&Xt[p][(mb0 + (mi << 4) + ml) * 72 + ko]);
#pragma unroll
      for (int ni = 0; ni < 2; ++ni)
        bf[ni] = *(const s16x8*)(&Xt[p][(nb0 + (ni << 4) + ml) * 72 + ko]);
#pragma unroll
      for (int mi = 0; mi < 2; ++mi)
#pragma unroll
        for (int ni = 0; ni < 2; ++ni)
          acc[mi][ni] = __builtin_amdgcn_mfma_f32_16x16x32_bf16(
              af[mi], bf[ni], acc[mi][ni], 0, 0, 0);
    }
    p ^= 1;
  }
  // gram accumulate: C/D layout col=lane&15, row=(lane>>4)*4+reg
  float* gb = gram + (size_t)b * 4096;
  const int crow = (lane >> 4) << 2;
  const int ccol = lane & 15;
#pragma unroll
  for (int mi = 0; mi < 2; ++mi)
#pragma unroll
    for (int ni = 0; ni < 2; ++ni) {
      const int gr0 = mb0 + (mi << 4) + crow;
      const int gc = nb0 + (ni << 4) + ccol;
#pragma unroll
      for (int rg = 0; rg < 4; ++rg)
        atomicAdd(&gb[(gr0 + rg) * 64 + gc], acc[mi][ni][rg]);
    }
}

// ============ kernel 34: block-specialized spectral (0..127) + final (128..255) ============
__global__ __launch_bounds__(512) void k34(const float* __restrict__ xmean,
    const float* __restrict__ gram, const float* __restrict__ colsum,
    const unsigned* __restrict__ hist, const float* __restrict__ scal,
    const int* __restrict__ firstg, float* __restrict__ out) {
  __shared__ __align__(16) char arena[49152];
  __shared__ float sred[8];
  __shared__ float smv[8];
  __shared__ int smi[8];
  __shared__ float cssh[64];
  __shared__ float sdsh[64];
  __shared__ float osv_s[6];
  const int tid = threadIdx.x;

  if (blockIdx.x < 128) {
    // ================= spectral path =================
    const int b = blockIdx.x;
    float* xm = (float*)arena;
    float* re = xm + 4096;
    float* im = re + 4096;
    const float* xb = xmean + (size_t)b * TT;
    for (int i = tid; i < TT; i += 512) xm[i] = xb[i];
    __syncthreads();
    float ls = 0.f;
    for (int i = tid; i < TT; i += 512) ls += xm[i];
    const float meanv = brs8(ls, sred, tid) * (1.f / TT);
    float tnum = 0.f, roc = 0.f;
    int pk = 0, zc = 0;
    for (int i = tid; i < TT; i += 512) {
      const float xi = xm[i];
      tnum += ((float)i - 2047.5f) * (xi - meanv);
      if (i < TT - 1) {
        const float d1 = xm[i + 1] - xi;
        roc += fabsf(d1);
        if (i >= 1) {
          const float d0 = xi - xm[i - 1];
          if (d1 * d0 < 0.f) ++pk;
        }
      }
      if (i >= 1) {
        if ((xi - meanv) * (xm[i - 1] - meanv) < 0.f) ++zc;
      }
    }
    tnum = brs8(tnum, sred, tid);
    roc = brs8(roc, sred, tid);
    const float pkf = brs8((float)pk, sred, tid);
    const float zcf = brs8((float)zc, sred, tid);
    if (tid == 0) {
      out[b * 17 + 1] = tnum / 5726622720.0f;
      out[b * 17 + 9] = pkf * (1.f / 4094.f);
      out[b * 17 + 10] = zcf * (1.f / 4095.f);
      out[b * 17 + 11] = roc * (1.f / 4095.f);
    }
    // radix-2 DIT FFT in LDS
    for (int i = tid; i < TT; i += 512) {
      re[i] = xm[__brev((unsigned)i) >> 20];
      im[i] = 0.f;
    }
    __syncthreads();
    int l2h = 0;
    for (int len = 2; len <= TT; len <<= 1, ++l2h) {
      const int half = len >> 1;
      const float ab = -6.283185307179586f / (float)len;
      for (int j = tid; j < TT / 2; j += 512) {
        const int pos = j & (half - 1);
        const int i0 = ((j >> l2h) << (l2h + 1)) + pos;
        const int i1 = i0 + half;
        float sn, cn;
        __sincosf(ab * (float)pos, &sn, &cn);
        const float vr = re[i1], vi = im[i1];
        const float tr = cn * vr - sn * vi;
        const float ti = cn * vi + sn * vr;
        const float ur = re[i0], ui = im[i0];
        re[i0] = ur + tr; im[i0] = ui + ti;
        re[i1] = ur - tr; im[i1] = ui - ti;
      }
      __syncthreads();
    }
    // power spectrum: sum, argmax, entropy over bins 0..2048
    float ps = 0.f, bmaxv = -1.f;
    int bidx = 0;
    for (int k = tid; k <= 2048; k += 512) {
      const float p = re[k] * re[k] + im[k] * im[k];
      ps += p;
      if (p > bmaxv) { bmaxv = p; bidx = k; }
    }
    ps = brs8(ps, sred, tid);
#pragma unroll
    for (int o = 32; o; o >>= 1) {
      const float ov = __shfl_xor(bmaxv, o);
      const int oi = __shfl_xor(bidx, o);
      if (ov > bmaxv || (ov == bmaxv && oi < bidx)) { bmaxv = ov; bidx = oi; }
    }
    if ((tid & 63) == 0) { smv[tid >> 6] = bmaxv; smi[tid >> 6] = bidx; }
    __syncthreads();
    float ent = 0.f;
    const float inv = 1.f / (ps + 1e-8f);
    for (int k = tid; k <= 2048; k += 512) {
      const float p = (re[k] * re[k] + im[k] * im[k]) * inv;
      ent -= p * __logf(p + 1e-8f);
    }
    ent = brs8(ent, sred, tid);
    if (tid == 0) {
      float bv = smv[0]; int bi = smi[0];
      for (int w = 1; w < 8; ++w)
        if (smv[w] > bv || (smv[w] == bv && smi[w] < bi)) { bv = smv[w]; bi = smi[w]; }
      out[b * 17 + 2] = (float)bi * (1.f / 2048.f);
      out[b * 17 + 3] = ent;
    }
  } else {
    // ================= final path =================
    const int b = blockIdx.x - 128;
    float* Lg = (float*)arena;                          // 64 x 65
    unsigned* h = (unsigned*)(arena + 16640);           // 4096
    unsigned* cumc = (unsigned*)(arena + 16640 + 16384);// 256
    if (tid < 64) cssh[tid] = colsum[b * 64 + tid];
    for (int i = tid; i < 4096; i += 512) h[i] = hist[(size_t)b * 4096 + i];
    __syncthreads();
    const float* gb = gram + (size_t)b * 4096;
    for (int i = tid; i < 4096; i += 512) {
      const int d = i >> 6, e = i & 63;
      Lg[d * 65 + e] = gb[i] - cssh[d] * cssh[e] * (1.f / 4096.f);
    }
    unsigned chs_own = 0;
    if (tid < 256) {
#pragma unroll
      for (int j = 0; j < 16; ++j) chs_own += h[(tid << 4) + j];
      cumc[tid] = chs_own;
    }
    __syncthreads();
    if (tid < 64) sdsh[tid] = sqrtf(Lg[tid * 65 + tid] * (1.f / 4095.f));
    // inclusive scan over 256 coarse bins
    for (int off = 1; off < 256; off <<= 1) {
      unsigned add = 0;
      if (tid < 256 && tid >= off) add = cumc[tid - off];
      __syncthreads();
      if (tid < 256) cumc[tid] += add;
      __syncthreads();
    }
    float mcs = 0.f, trc = 0.f;
    for (int i = tid; i < 4096; i += 512) {
      const int d = i >> 6, e = i & 63;
      const float gv = Lg[d * 65 + e];
      if (d != e) mcs += (gv * (1.f / 4095.f)) / (sdsh[d] * sdsh[e] + 1e-8f);
      else trc += gv;
    }
    mcs = brs8(mcs, sred, tid);
    trc = brs8(trc, sred, tid);
    // parallel quantile refinement
    if (tid < 256) {
      const unsigned ranks[6] = {65535u, 65536u, 131071u, 131072u, 196607u, 196608u};
      const unsigned incl = cumc[tid];
      const unsigned excl = incl - chs_own;
#pragma unroll
      for (int qi = 0; qi < 6; ++qi) {
        const unsigned r = ranks[qi];
        if (excl <= r && r < incl) {
          int bin = tid << 4;
          unsigned cum = excl;
          while (bin < 4095 && cum + h[bin] <= r) { cum += h[bin]; ++bin; }
          const float cnt = (float)max(h[bin], 1u);
          osv_s[qi] = ((float)bin * (1.f / 256.f) - 8.f) +
                      (((float)(r - cum) + 0.5f) / cnt) * (1.f / 256.f);
        }
      }
    }
    // power iteration on wave 0
    float lam = 0.f;
    if (tid < 64) {
      const float* rowp = &Lg[tid * 65];
      float v = 1.f + 0.001f * (float)tid;
      float n2 = 1.f;
      for (int it = 0; it < 48; ++it) {
        float w0 = 0.f, w1 = 0.f, w2 = 0.f, w3 = 0.f;
#pragma unroll
        for (int e = 0; e < 64; e += 4) {
          w0 = fmaf(rowp[e],     __shfl(v, e),     w0);
          w1 = fmaf(rowp[e + 1], __shfl(v, e + 1), w1);
          w2 = fmaf(rowp[e + 2], __shfl(v, e + 2), w2);
          w3 = fmaf(rowp[e + 3], __shfl(v, e + 3), w3);
        }
        const float w = (w0 + w1) + (w2 + w3);
        n2 = w * w;
#pragma unroll
        for (int o = 32; o; o >>= 1) n2 += __shfl_xor(n2, o);
        v = w * rsqrtf(n2);
      }
      lam = sqrtf(n2);
    }
    __syncthreads();
    if (tid == 0) {
      const float q25 = 0.25f * osv_s[0] + 0.75f * osv_s[1];
      const float q50 = 0.5f * (osv_s[2] + osv_s[3]);
      const float q75 = 0.75f * osv_s[4] + 0.25f * osv_s[5];
      const float N = 262144.f;
      const float m1 = scal[1 * TB + b] / N;
      const float M2 = scal[2 * TB + b] / N;
      const float M3 = scal[3 * TB + b] / N;
      const float M4 = scal[4 * TB + b] / N;
      const float mu2 = M2 - m1 * m1;
      const float mu3 = M3 - 3.f * m1 * M2 + 2.f * m1 * m1 * m1;
      const float mu4 = M4 - 4.f * m1 * M3 + 6.f * m1 * m1 * M2 - 3.f * m1 * m1 * m1 * m1;
      const float skew = mu3 / (sqrtf(mu2) * mu2 + 1e-8f);
      const float kurt = mu4 / (mu2 * mu2 + 1e-8f);
      const float acv = scal[0 * TB + b] * (1.f / 262080.f);
      const float msum = scal[5 * TB + b];
      const float o2s = scal[6 * TB + b];
      const float missing = 1.f - msum / 262144.f;
      const float sdm = msum * (1.f / 64.f) * (1.f / 4096.f);
      const float dvar = (o2s * (1.f / 4096.f) - 4096.f * sdm * sdm) * (1.f / 4095.f);
      const int fm = firstg[b];
      const float fobs = fm > 0 ? (float)(4096 - fm) * (1.f / 4096.f) : 0.f;
      float* ob = out + b * 17;
      ob[0] = acv;
      ob[4] = skew; ob[5] = kurt;
      ob[6] = q25; ob[7] = q50; ob[8] = q75;
      ob[12] = missing; ob[13] = dvar; ob[14] = fobs;
      ob[15] = mcs / (4032.f + 1e-8f);
      ob[16] = lam / trc;
    }
  }
}

extern "C" void kernel_launch(void* const* d_in, const int* in_sizes, int n_in,
                              void* d_out, int out_size, void* d_ws, size_t ws_size,
                              hipStream_t stream) {
  (void)in_sizes; (void)n_in; (void)out_size; (void)ws_size;
  const float* x = (const float*)d_in[0];
  const float* mask = (const float*)d_in[1];
  float* out = (float*)d_out;
  char* ws = (char*)d_ws;
  float* gram = (float*)(ws + GRAM_OFF);
  unsigned* hist = (unsigned*)(ws + HIST_OFF);
  float* colsum = (float*)(ws + COLSUM_OFF);
  float* scal = (float*)(ws + SCAL_OFF);
  int* firstg = (int*)(ws + FIRST_OFF);
  float* xmean = (float*)(ws + XMEAN_OFF);

  hipMemsetAsync(d_ws, 0, ZERO_BYTES, stream);

  dim3 g1(8, TB);
  kA_stats<<<g1, 256, 0, stream>>>(x, mask, xmean, hist, colsum, scal, firstg);
  kB_gram<<<g1, 256, 0, stream>>>(x, gram);
  k34<<<256, 512, 0, stream>>>(xmean, gram, colsum, hist, scal, firstg, out);
}